// Round 1
// baseline (1063.383 us; speedup 1.0000x reference)
//
#include <hip/hip_runtime.h>
#include <hip/hip_bf16.h>

typedef unsigned short u16;

constexpr int kHW    = 16384;        // 128*128
constexpr int kC     = 192;
constexpr int kC3    = 576;
constexpr int kNH    = 4;
constexpr int kHD    = 48;
constexpr int kB     = 8;
constexpr int kNCH   = 8;            // n-chunks for split-K of S
constexpr int kCHUNK = kHW / kNCH;   // 2048

__device__ __forceinline__ float bfu2f(unsigned u) { return __uint_as_float(u << 16); }
__device__ __forceinline__ u16 f2bfu(float f) {
  unsigned x = __float_as_uint(f);
  unsigned r = (x + 0x7fffu + ((x >> 16) & 1u)) >> 16;  // RNE
  return (u16)r;
}

// ---------------------------------------------------------------------------
// K1 / K5: Out[b][o][n] = sum_k W[b?][o][k] * In[b][k][n],  K = 192.
// Block tile: 64 o x 256 n, 256 threads, each thread 8x8 register tile.
// ---------------------------------------------------------------------------
template <bool IN_BF16, bool OUT_BF16>
__global__ __launch_bounds__(256) void gemm_nk(
    const float* __restrict__ Wbase, long wStride,
    const void* __restrict__ InBase, long inStride,
    void* __restrict__ OutBase, long outStride) {
  const int o0 = blockIdx.x * 64;
  const int n0 = blockIdx.y * 256;
  const int b  = blockIdx.z;
  const int t  = threadIdx.x;
  const int to = t >> 5, tn = t & 31;
  const float* W = Wbase + (size_t)b * wStride;

  __shared__ float wT[32][65];    // [k][o], padded (odd stride -> conflict-free transpose write)
  __shared__ float xs[32][256];   // [k][n]

  float acc[8][8];
#pragma unroll
  for (int r = 0; r < 8; ++r)
#pragma unroll
    for (int c = 0; c < 8; ++c) acc[r][c] = 0.f;

  for (int k0 = 0; k0 < kC; k0 += 32) {
    // stage W tile (transposed): global read coalesced along k
#pragma unroll
    for (int i = 0; i < 8; ++i) {
      int idx = t + i * 256;
      int oo = idx >> 5, kk = idx & 31;
      wT[kk][oo] = W[(size_t)(o0 + oo) * kC + k0 + kk];
    }
    // stage In tile
    if constexpr (IN_BF16) {
      const u16* Ib = (const u16*)InBase + (size_t)b * inStride;
#pragma unroll
      for (int i = 0; i < 8; ++i) {
        int e = (t + i * 256) * 4;
        int kk = e >> 8, nn = e & 255;
        uint2 raw = *(const uint2*)(Ib + (size_t)(k0 + kk) * kHW + n0 + nn);
        xs[kk][nn + 0] = bfu2f(raw.x & 0xffffu);
        xs[kk][nn + 1] = bfu2f(raw.x >> 16);
        xs[kk][nn + 2] = bfu2f(raw.y & 0xffffu);
        xs[kk][nn + 3] = bfu2f(raw.y >> 16);
      }
    } else {
      const float* If = (const float*)InBase + (size_t)b * inStride;
#pragma unroll
      for (int i = 0; i < 8; ++i) {
        int e = (t + i * 256) * 4;
        int kk = e >> 8, nn = e & 255;
        float4 v = *(const float4*)(If + (size_t)(k0 + kk) * kHW + n0 + nn);
        xs[kk][nn + 0] = v.x;
        xs[kk][nn + 1] = v.y;
        xs[kk][nn + 2] = v.z;
        xs[kk][nn + 3] = v.w;
      }
    }
    __syncthreads();
#pragma unroll 4
    for (int k = 0; k < 32; ++k) {
      float wr[8], xr[8];
#pragma unroll
      for (int r = 0; r < 8; ++r) wr[r] = wT[k][to * 8 + r];   // 2 addrs/wave (broadcast)
#pragma unroll
      for (int c = 0; c < 8; ++c) xr[c] = xs[k][tn * 8 + c];   // contiguous b128/lane
#pragma unroll
      for (int r = 0; r < 8; ++r)
#pragma unroll
        for (int c = 0; c < 8; ++c) acc[r][c] += wr[r] * xr[c];
    }
    __syncthreads();
  }

  if constexpr (OUT_BF16) {
    u16* Ob = (u16*)OutBase + (size_t)b * outStride;
#pragma unroll
    for (int r = 0; r < 8; ++r) {
      unsigned u0 = (unsigned)f2bfu(acc[r][0]) | ((unsigned)f2bfu(acc[r][1]) << 16);
      unsigned u1 = (unsigned)f2bfu(acc[r][2]) | ((unsigned)f2bfu(acc[r][3]) << 16);
      unsigned u2 = (unsigned)f2bfu(acc[r][4]) | ((unsigned)f2bfu(acc[r][5]) << 16);
      unsigned u3 = (unsigned)f2bfu(acc[r][6]) | ((unsigned)f2bfu(acc[r][7]) << 16);
      uint4 pv = {u0, u1, u2, u3};
      *(uint4*)(Ob + (size_t)(o0 + to * 8 + r) * kHW + n0 + tn * 8) = pv;
    }
  } else {
    float* Of = (float*)OutBase + (size_t)b * outStride;
#pragma unroll
    for (int r = 0; r < 8; ++r) {
      float* dst = Of + (size_t)(o0 + to * 8 + r) * kHW + n0 + tn * 8;
      float4 a = {acc[r][0], acc[r][1], acc[r][2], acc[r][3]};
      float4 bb = {acc[r][4], acc[r][5], acc[r][6], acc[r][7]};
      *(float4*)dst = a;
      *(float4*)(dst + 4) = bb;
    }
  }
}

// ---------------------------------------------------------------------------
// K2: depthwise 3x3, padding=1. block = 2 rows x 128 cols of one (b,ch) image.
// ---------------------------------------------------------------------------
__global__ __launch_bounds__(256) void dwconv3x3(
    const u16* __restrict__ in, const float* __restrict__ wdw, u16* __restrict__ out) {
  const int bc = blockIdx.y;  // b*576 + ch
  const int ch = bc % kC3;
  const int h = blockIdx.x * 2 + (threadIdx.x >> 7);
  const int w = threadIdx.x & 127;
  const u16* p = in + (size_t)bc * kHW;
  const float* wt = wdw + ch * 9;  // block-uniform -> scalar loads
  float s = 0.f;
#pragma unroll
  for (int dy = 0; dy < 3; ++dy) {
    int hh = h + dy - 1;
    if (hh < 0 || hh > 127) continue;
#pragma unroll
    for (int dx = 0; dx < 3; ++dx) {
      int ww = w + dx - 1;
      if (ww < 0 || ww > 127) continue;
      s += wt[dy * 3 + dx] * bfu2f(p[hh * 128 + ww]);
    }
  }
  out[(size_t)bc * kHW + h * 128 + w] = f2bfu(s);
}

// ---------------------------------------------------------------------------
// K3: split-K partials of S[c][d] = sum_n q[c,n]*k[d,n] (raw, un-normalized)
//     plus per-row sum-of-squares partials. Deterministic (no atomics).
// grid: (chunk, bh). block 256 = 16x16, each thread 3c x 3d.
// ---------------------------------------------------------------------------
__global__ __launch_bounds__(256) void qk_partial(
    const u16* __restrict__ qkv, float* __restrict__ Spart,
    float* __restrict__ qsqp, float* __restrict__ ksqp) {
  const int chunk = blockIdx.x;
  const int bh = blockIdx.y;
  const int b = bh >> 2, hh = bh & 3;
  const int nbase = chunk * kCHUNK;
  const u16* qp = qkv + (size_t)(b * kC3 + hh * kHD) * kHW;
  const u16* kp = qkv + (size_t)(b * kC3 + kC + hh * kHD) * kHW;
  __shared__ float qs[32][53];  // [j][c], odd stride -> conflict-free
  __shared__ float ks[32][53];
  const int t = threadIdx.x, tc = t >> 4, td = t & 15;
  float acc[3][3];
#pragma unroll
  for (int i = 0; i < 3; ++i)
#pragma unroll
    for (int j = 0; j < 3; ++j) acc[i][j] = 0.f;
  float nq = 0.f, nk = 0.f;

  for (int tile = 0; tile < kCHUNK / 32; ++tile) {
    const int n0 = nbase + tile * 32;
#pragma unroll
    for (int i = 0; i < 6; ++i) {  // 1536 elems per operand / 256 threads
      int idx = t + i * 256;
      int c = idx >> 5, j = idx & 31;
      qs[j][c] = bfu2f(qp[(size_t)c * kHW + n0 + j]);
      ks[j][c] = bfu2f(kp[(size_t)c * kHW + n0 + j]);
    }
    __syncthreads();
#pragma unroll 4
    for (int j = 0; j < 32; ++j) {
      float a0 = qs[j][tc * 3 + 0], a1 = qs[j][tc * 3 + 1], a2 = qs[j][tc * 3 + 2];
      float b0 = ks[j][td * 3 + 0], b1 = ks[j][td * 3 + 1], b2 = ks[j][td * 3 + 2];
      acc[0][0] += a0 * b0; acc[0][1] += a0 * b1; acc[0][2] += a0 * b2;
      acc[1][0] += a1 * b0; acc[1][1] += a1 * b1; acc[1][2] += a1 * b2;
      acc[2][0] += a2 * b0; acc[2][1] += a2 * b1; acc[2][2] += a2 * b2;
    }
    if (t < 48) {
#pragma unroll 4
      for (int j = 0; j < 32; ++j) { float v = qs[j][t]; nq += v * v; }
    } else if (t < 96) {
#pragma unroll 4
      for (int j = 0; j < 32; ++j) { float v = ks[j][t - 48]; nk += v * v; }
    }
    __syncthreads();
  }

  float* Sp = Spart + ((size_t)chunk * 32 + bh) * (kHD * kHD);
#pragma unroll
  for (int i = 0; i < 3; ++i)
#pragma unroll
    for (int j = 0; j < 3; ++j)
      Sp[(tc * 3 + i) * kHD + td * 3 + j] = acc[i][j];
  if (t < 48) qsqp[(chunk * 32 + bh) * kHD + t] = nq;
  else if (t < 96) ksqp[(chunk * 32 + bh) * kHD + (t - 48)] = nk;
}

// ---------------------------------------------------------------------------
// K3b: reduce partials, fold norms (F.normalize eps=1e-12) + temperature,
//      row softmax over d. One block per (b,h).
// ---------------------------------------------------------------------------
__global__ __launch_bounds__(256) void attn_softmax(
    const float* __restrict__ Spart, const float* __restrict__ qsqp,
    const float* __restrict__ ksqp, const float* __restrict__ temp,
    float* __restrict__ attn) {
  const int bh = blockIdx.x, hh = bh & 3;
  const int t = threadIdx.x;
  __shared__ float S[kHD * kHD];
  __shared__ float qn[kHD], kinv[kHD];
  for (int p = t; p < kHD * kHD; p += 256) {
    float s = 0.f;
#pragma unroll
    for (int c = 0; c < kNCH; ++c) s += Spart[((size_t)c * 32 + bh) * (kHD * kHD) + p];
    S[p] = s;
  }
  if (t < 48) {
    float s = 0.f;
#pragma unroll
    for (int c = 0; c < kNCH; ++c) s += qsqp[(c * 32 + bh) * kHD + t];
    qn[t] = sqrtf(s);
  } else if (t < 96) {
    float s = 0.f;
#pragma unroll
    for (int c = 0; c < kNCH; ++c) s += ksqp[(c * 32 + bh) * kHD + (t - 48)];
    kinv[t - 48] = 1.f / fmaxf(sqrtf(s), 1e-12f);
  }
  __syncthreads();
  if (t < 48) {
    const float T = temp[hh];
    const float sq = T / fmaxf(qn[t], 1e-12f);
    float m = -3.4e38f;
    for (int d = 0; d < kHD; ++d) {
      float v = S[t * kHD + d] * sq * kinv[d];
      S[t * kHD + d] = v;
      m = fmaxf(m, v);
    }
    float sum = 0.f;
    for (int d = 0; d < kHD; ++d) {
      float e = expf(S[t * kHD + d] - m);
      S[t * kHD + d] = e;
      sum += e;
    }
    const float inv = 1.f / sum;
    float* A = attn + (size_t)bh * (kHD * kHD) + t * kHD;
    for (int d = 0; d < kHD; ++d) A[d] = S[t * kHD + d] * inv;
  }
}

// ---------------------------------------------------------------------------
// K4: fold w_out through attention: M[b][o][h*48+d] = sum_c w_out[o][h*48+c]*attn[b,h,c,d]
// ---------------------------------------------------------------------------
__global__ __launch_bounds__(256) void make_m(
    const float* __restrict__ wout, const float* __restrict__ attn, float* __restrict__ M) {
  int g = blockIdx.x * 256 + threadIdx.x;
  if (g >= kB * kC * kC) return;
  int j = g % kC;
  int o = (g / kC) % kC;
  int b = g / (kC * kC);
  int hh = j / kHD, d = j % kHD;
  const float* A = attn + (size_t)(b * kNH + hh) * (kHD * kHD) + d;
  const float* wo = wout + (size_t)o * kC + hh * kHD;
  float s = 0.f;
#pragma unroll
  for (int c = 0; c < kHD; ++c) s += wo[c] * A[c * kHD];
  M[g] = s;
}

// ---------------------------------------------------------------------------
extern "C" void kernel_launch(void* const* d_in, const int* in_sizes, int n_in,
                              void* d_out, int out_size, void* d_ws, size_t ws_size,
                              hipStream_t stream) {
  const float* x    = (const float*)d_in[0];  // [8,192,128,128]
  const float* wqkv = (const float*)d_in[1];  // [576,192]
  const float* wdw  = (const float*)d_in[2];  // [576,1,3,3]
  const float* temp = (const float*)d_in[3];  // [1,4,1,1]
  const float* wout = (const float*)d_in[4];  // [192,192]

  size_t off = 0;
  u16* qkv1 = (u16*)((char*)d_ws + off); off += (size_t)kB * kC3 * kHW * 2;         // 151 MB
  u16* qkv2 = (u16*)((char*)d_ws + off); off += (size_t)kB * kC3 * kHW * 2;         // 151 MB
  float* Spart = (float*)((char*)d_ws + off); off += (size_t)kNCH * 32 * kHD * kHD * 4;
  float* qsqp  = (float*)((char*)d_ws + off); off += (size_t)kNCH * 32 * kHD * 4;
  float* ksqp  = (float*)((char*)d_ws + off); off += (size_t)kNCH * 32 * kHD * 4;
  float* attn  = (float*)((char*)d_ws + off); off += (size_t)32 * kHD * kHD * 4;
  float* Mbuf  = (float*)((char*)d_ws + off); off += (size_t)kB * kC * kC * 4;
  if (off > ws_size) return;  // insufficient workspace -> fail visibly

  // K1: qkv = w_qkv @ x   (f32 in, bf16 out)
  gemm_nk<false, true><<<dim3(kC3 / 64, kHW / 256, kB), 256, 0, stream>>>(
      wqkv, 0L, (const void*)x, (long)kC * kHW, (void*)qkv1, (long)kC3 * kHW);
  // K2: depthwise 3x3
  dwconv3x3<<<dim3(64, kB * kC3), 256, 0, stream>>>(qkv1, wdw, qkv2);
  // K3: raw S partials + sumsq partials
  qk_partial<<<dim3(kNCH, 32), 256, 0, stream>>>(qkv2, Spart, qsqp, ksqp);
  // K3b: reduce + normalize + softmax
  attn_softmax<<<dim3(32), 256, 0, stream>>>(Spart, qsqp, ksqp, temp, attn);
  // K4: M = w_out folded through attn
  make_m<<<dim3((kB * kC * kC + 255) / 256), 256, 0, stream>>>(wout, attn, Mbuf);
  // K5: out = M @ v   (bf16 in, f32 out); v = channels 384..575 of qkv2
  gemm_nk<true, false><<<dim3(kC / 64, kHW / 256, kB), 256, 0, stream>>>(
      Mbuf, (long)kC * kC, (const void*)(qkv2 + (size_t)(2 * kC) * kHW),
      (long)kC3 * kHW, d_out, (long)kC * kHW);
}

// Round 2
// 375.136 us; speedup vs baseline: 2.8347x; 2.8347x over previous
//
#include <hip/hip_runtime.h>
#include <hip/hip_bf16.h>

typedef unsigned short u16;
typedef unsigned int u32;

constexpr int kHW  = 16384;   // 128*128
constexpr int kC   = 192;
constexpr int kC3  = 576;
constexpr int kHD  = 48;
constexpr int kB   = 8;
constexpr int kNCH = 64;      // split-K chunks for S (each = 256 n)

typedef __attribute__((ext_vector_type(8))) short bfx8;  // 8 bf16 in 4 VGPRs
typedef __attribute__((ext_vector_type(4))) float fx4;

__device__ __forceinline__ float bfu2f(u32 u) { return __uint_as_float(u << 16); }
__device__ __forceinline__ u16 f2bfu(float f) {
  u32 x = __float_as_uint(f);
  return (u16)((x + 0x7fffu + ((x >> 16) & 1u)) >> 16);  // RNE
}

// ---------------------------------------------------------------------------
// P1: f32 -> bf16 cast (for w_qkv)
// ---------------------------------------------------------------------------
__global__ __launch_bounds__(256) void cast_f32_bf16(
    const float* __restrict__ in, u16* __restrict__ out, int n) {
  int i = blockIdx.x * 256 + threadIdx.x;
  if (i < n) out[i] = f2bfu(in[i]);
}

// ---------------------------------------------------------------------------
// P2: x [b][192][16384] f32 -> xT [b][16384][192] bf16 (64x64 LDS tile)
// ---------------------------------------------------------------------------
__global__ __launch_bounds__(256) void transpose_cast_x(
    const float* __restrict__ X, u16* __restrict__ XT) {
  const int n0 = blockIdx.x * 64, c0 = blockIdx.y * 64, b = blockIdx.z;
  const float* xp = X + (size_t)b * kC * kHW;
  u16* xtp = XT + (size_t)b * kHW * kC;
  __shared__ u16 tile[64][80];  // 160B rows: 16B-aligned, conflict-free writes
  const int t = threadIdx.x;
#pragma unroll
  for (int i = 0; i < 4; ++i) {
    int idx = t + i * 256;                 // 1024 float4 = 64c x 64n
    int c = idx >> 4, n4 = (idx & 15) * 4;
    float4 v = *(const float4*)(xp + (size_t)(c0 + c) * kHW + n0 + n4);
    u32 lo = (u32)f2bfu(v.x) | ((u32)f2bfu(v.y) << 16);
    u32 hi = (u32)f2bfu(v.z) | ((u32)f2bfu(v.w) << 16);
    *(uint2*)(&tile[c][n4]) = make_uint2(lo, hi);
  }
  __syncthreads();
  const int r = t >> 2, ch = (t & 3) * 16;
  u32 w[8];
#pragma unroll
  for (int j = 0; j < 8; ++j)
    w[j] = (u32)tile[ch + 2 * j][r] | ((u32)tile[ch + 2 * j + 1][r] << 16);
  u16* dst = xtp + (size_t)(n0 + r) * kC + c0 + ch;
  *(uint4*)dst       = make_uint4(w[0], w[1], w[2], w[3]);
  *(uint4*)(dst + 8) = make_uint4(w[4], w[5], w[6], w[7]);
}

// ---------------------------------------------------------------------------
// K2b: v [b][c][n] bf16 -> vT [b][n][c] bf16
// ---------------------------------------------------------------------------
__global__ __launch_bounds__(256) void transpose_bf16(
    const u16* __restrict__ V, long srcBatch, u16* __restrict__ VT, long dstBatch) {
  const int n0 = blockIdx.x * 64, c0 = blockIdx.y * 64, b = blockIdx.z;
  const u16* vp = V + (size_t)b * srcBatch;
  u16* vtp = VT + (size_t)b * dstBatch;
  __shared__ u16 tile[64][80];
  const int t = threadIdx.x;
#pragma unroll
  for (int i = 0; i < 2; ++i) {
    int idx = t + i * 256;                 // 512 uint4 = 64c x 64n
    int c = idx >> 3, n8 = (idx & 7) * 8;
    *(uint4*)(&tile[c][n8]) = *(const uint4*)(vp + (size_t)(c0 + c) * kHW + n0 + n8);
  }
  __syncthreads();
  const int r = t >> 2, ch = (t & 3) * 16;
  u32 w[8];
#pragma unroll
  for (int j = 0; j < 8; ++j)
    w[j] = (u32)tile[ch + 2 * j][r] | ((u32)tile[ch + 2 * j + 1][r] << 16);
  u16* dst = vtp + (size_t)(n0 + r) * kC + c0 + ch;
  *(uint4*)dst       = make_uint4(w[0], w[1], w[2], w[3]);
  *(uint4*)(dst + 8) = make_uint4(w[4], w[5], w[6], w[7]);
}

// ---------------------------------------------------------------------------
// K1/K5: MFMA GEMM. Out[b][o][n] = sum_k A[b?][o][k] * BT[b][n][k], K=192.
// Block: 64 o x 256 n, 4 waves side-by-side in n (wave tile 64x64).
// LDS slot-XOR swizzle: byte(row,k16slot) = row*128 + ((slot ^ (row&7))*16)
// -> both ds_write_b128 staging and ds_read_b128 frag reads conflict-free.
// A/B frags: row/col = lane&15, k = (lane>>4)*8 + j (identical k-map on both
// operands, so any k-permutation cancels). C/D: col=lane&15, row=(lane>>4)*4+r.
// ---------------------------------------------------------------------------
template <bool OUT_BF16>
__global__ __launch_bounds__(256) void gemm_mfma(
    const u16* __restrict__ Abase, long aStride,
    const u16* __restrict__ Bbase, long bStride,
    void* __restrict__ OutBase, long oStride) {
  const int b = blockIdx.z;
  const int o0 = blockIdx.x * 64;
  const int n0 = blockIdx.y * 256;
  const int t = threadIdx.x;
  const int lane = t & 63, wv = t >> 6;
  const int fr = lane & 15, fg = lane >> 4;

  __shared__ u16 As[64 * 64];    // 8 KB
  __shared__ u16 Bs[256 * 64];   // 32 KB

  const u16* A  = Abase + (size_t)b * aStride;
  const u16* Bp = Bbase + (size_t)b * bStride;

  fx4 acc[4][4];
#pragma unroll
  for (int m = 0; m < 4; ++m)
#pragma unroll
    for (int n = 0; n < 4; ++n) acc[m][n] = (fx4){0.f, 0.f, 0.f, 0.f};

  for (int k0 = 0; k0 < kC; k0 += 64) {
    if (k0) __syncthreads();
    // stage A tile (64 rows x 64 k): 512 uint4
#pragma unroll
    for (int i = 0; i < 2; ++i) {
      int idx = t + i * 256;
      int row = idx >> 3, sl = idx & 7;
      uint4 v = *(const uint4*)(A + (size_t)(o0 + row) * kC + k0 + sl * 8);
      *(uint4*)(As + row * 64 + ((sl ^ (row & 7)) * 8)) = v;
    }
    // stage B tile (256 rows x 64 k): 2048 uint4
#pragma unroll
    for (int i = 0; i < 8; ++i) {
      int idx = t + i * 256;
      int row = idx >> 3, sl = idx & 7;
      uint4 v = *(const uint4*)(Bp + (size_t)(n0 + row) * kC + k0 + sl * 8);
      *(uint4*)(Bs + row * 64 + ((sl ^ (row & 7)) * 8)) = v;
    }
    __syncthreads();
#pragma unroll
    for (int ks = 0; ks < 2; ++ks) {
      bfx8 af[4], bf[4];
#pragma unroll
      for (int m = 0; m < 4; ++m) {
        int row = m * 16 + fr;
        af[m] = *(const bfx8*)(As + row * 64 + (((ks * 4 + fg) ^ (row & 7)) * 8));
      }
#pragma unroll
      for (int n = 0; n < 4; ++n) {
        int row = wv * 64 + n * 16 + fr;
        bf[n] = *(const bfx8*)(Bs + row * 64 + (((ks * 4 + fg) ^ (row & 7)) * 8));
      }
#pragma unroll
      for (int m = 0; m < 4; ++m)
#pragma unroll
        for (int n = 0; n < 4; ++n)
          acc[m][n] = __builtin_amdgcn_mfma_f32_16x16x32_bf16(af[m], bf[n], acc[m][n], 0, 0, 0);
    }
  }

  if constexpr (OUT_BF16) {
    u16* O = (u16*)OutBase + (size_t)b * oStride;
#pragma unroll
    for (int m = 0; m < 4; ++m)
#pragma unroll
      for (int n = 0; n < 4; ++n) {
        int col = n0 + wv * 64 + n * 16 + fr;
#pragma unroll
        for (int r = 0; r < 4; ++r)
          O[(size_t)(o0 + m * 16 + fg * 4 + r) * kHW + col] = f2bfu(acc[m][n][r]);
      }
  } else {
    float* O = (float*)OutBase + (size_t)b * oStride;
#pragma unroll
    for (int m = 0; m < 4; ++m)
#pragma unroll
      for (int n = 0; n < 4; ++n) {
        int col = n0 + wv * 64 + n * 16 + fr;
#pragma unroll
        for (int r = 0; r < 4; ++r)
          O[(size_t)(o0 + m * 16 + fg * 4 + r) * kHW + col] = acc[m][n][r];
      }
  }
}

// ---------------------------------------------------------------------------
// K2: depthwise 3x3 'SAME'. 8 outputs/thread, uint4 loads (8 bf16).
// ---------------------------------------------------------------------------
__global__ __launch_bounds__(256) void dwconv3x3(
    const u16* __restrict__ in, const float* __restrict__ wdw, u16* __restrict__ out) {
  const int tid = blockIdx.x * 256 + threadIdx.x;
  const int w8 = tid & 15;            // 16 col-groups of 8
  const int h  = (tid >> 4) & 127;
  const int bc = tid >> 11;
  const u16* p = in + (size_t)bc * kHW;
  const float* wt = wdw + (bc % kC3) * 9;  // block-uniform -> scalar loads
  float o[8] = {0, 0, 0, 0, 0, 0, 0, 0};
#pragma unroll
  for (int dy = 0; dy < 3; ++dy) {
    int hh = h + dy - 1;
    if ((unsigned)hh > 127u) continue;
    const u16* row = p + hh * 128;
    uint4 m = *(const uint4*)(row + w8 * 8);
    float v[10];
    v[1] = bfu2f(m.x & 0xffffu); v[2] = bfu2f(m.x >> 16);
    v[3] = bfu2f(m.y & 0xffffu); v[4] = bfu2f(m.y >> 16);
    v[5] = bfu2f(m.z & 0xffffu); v[6] = bfu2f(m.z >> 16);
    v[7] = bfu2f(m.w & 0xffffu); v[8] = bfu2f(m.w >> 16);
    v[0] = (w8 > 0)  ? bfu2f(row[w8 * 8 - 1]) : 0.f;
    v[9] = (w8 < 15) ? bfu2f(row[w8 * 8 + 8]) : 0.f;
    float w0 = wt[dy * 3], w1 = wt[dy * 3 + 1], w2 = wt[dy * 3 + 2];
#pragma unroll
    for (int j = 0; j < 8; ++j) o[j] += w0 * v[j] + w1 * v[j + 1] + w2 * v[j + 2];
  }
  u32 p0 = (u32)f2bfu(o[0]) | ((u32)f2bfu(o[1]) << 16);
  u32 p1 = (u32)f2bfu(o[2]) | ((u32)f2bfu(o[3]) << 16);
  u32 p2 = (u32)f2bfu(o[4]) | ((u32)f2bfu(o[5]) << 16);
  u32 p3 = (u32)f2bfu(o[6]) | ((u32)f2bfu(o[7]) << 16);
  *(uint4*)(out + (size_t)bc * kHW + h * 128 + w8 * 8) = make_uint4(p0, p1, p2, p3);
}

// ---------------------------------------------------------------------------
// K3: MFMA split-K of S[c][d] = sum_n q[c,n]*k[d,n] + sumsq partials.
// 1 wave/block computes full 48x48 for a 256-n chunk; frags loaded straight
// from global (n is the contraction axis and is contiguous).
// ---------------------------------------------------------------------------
__global__ __launch_bounds__(64) void qk_mfma(
    const u16* __restrict__ qkv, float* __restrict__ Spart,
    float* __restrict__ qsq, float* __restrict__ ksq) {
  const int chunk = blockIdx.x;
  const int bh = blockIdx.y;
  const int b = bh >> 2, hh = bh & 3;
  const u16* qp = qkv + (size_t)(b * kC3 + hh * kHD) * kHW;
  const u16* kp = qp + (size_t)kC * kHW;
  const int lane = threadIdx.x;
  const int fr = lane & 15, fg = lane >> 4;

  fx4 acc[3][3];
#pragma unroll
  for (int i = 0; i < 3; ++i)
#pragma unroll
    for (int j = 0; j < 3; ++j) acc[i][j] = (fx4){0.f, 0.f, 0.f, 0.f};
  float sq[3] = {0.f, 0.f, 0.f}, sk[3] = {0.f, 0.f, 0.f};

  for (int s = 0; s < 8; ++s) {
    const int n = chunk * 256 + s * 32 + fg * 8;
    bfx8 aq[3], ak[3];
#pragma unroll
    for (int tt = 0; tt < 3; ++tt) {
      aq[tt] = *(const bfx8*)(qp + (size_t)(tt * 16 + fr) * kHW + n);
      ak[tt] = *(const bfx8*)(kp + (size_t)(tt * 16 + fr) * kHW + n);
    }
#pragma unroll
    for (int i = 0; i < 3; ++i)
#pragma unroll
      for (int j = 0; j < 3; ++j)
        acc[i][j] = __builtin_amdgcn_mfma_f32_16x16x32_bf16(aq[i], ak[j], acc[i][j], 0, 0, 0);
#pragma unroll
    for (int tt = 0; tt < 3; ++tt)
#pragma unroll
      for (int j = 0; j < 8; ++j) {
        float a = bfu2f((u16)aq[tt][j]); sq[tt] += a * a;
        float c = bfu2f((u16)ak[tt][j]); sk[tt] += c * c;
      }
  }
#pragma unroll
  for (int tt = 0; tt < 3; ++tt) {
    sq[tt] += __shfl_xor(sq[tt], 16); sq[tt] += __shfl_xor(sq[tt], 32);
    sk[tt] += __shfl_xor(sk[tt], 16); sk[tt] += __shfl_xor(sk[tt], 32);
  }
  float* Sp = Spart + ((size_t)chunk * 32 + bh) * (kHD * kHD);
#pragma unroll
  for (int i = 0; i < 3; ++i)
#pragma unroll
    for (int j = 0; j < 3; ++j)
#pragma unroll
      for (int r = 0; r < 4; ++r)
        Sp[(i * 16 + fg * 4 + r) * kHD + j * 16 + fr] = acc[i][j][r];
  if (fg == 0) {
#pragma unroll
    for (int tt = 0; tt < 3; ++tt) {
      qsq[((size_t)chunk * 32 + bh) * kHD + tt * 16 + fr] = sq[tt];
      ksq[((size_t)chunk * 32 + bh) * kHD + tt * 16 + fr] = sk[tt];
    }
  }
}

// ---------------------------------------------------------------------------
// K3b: reduce partials, fold norms (eps=1e-12) + temperature, row softmax.
// ---------------------------------------------------------------------------
__global__ __launch_bounds__(256) void attn_softmax(
    const float* __restrict__ Spart, const float* __restrict__ qsqp,
    const float* __restrict__ ksqp, const float* __restrict__ temp,
    float* __restrict__ attn) {
  const int bh = blockIdx.x, hh = bh & 3;
  const int t = threadIdx.x;
  __shared__ float S[kHD * kHD];
  __shared__ float qn[kHD], kinv[kHD];
  for (int p = t; p < kHD * kHD; p += 256) {
    float s = 0.f;
    for (int c = 0; c < kNCH; ++c) s += Spart[((size_t)c * 32 + bh) * (kHD * kHD) + p];
    S[p] = s;
  }
  if (t < 48) {
    float s = 0.f;
    for (int c = 0; c < kNCH; ++c) s += qsqp[((size_t)c * 32 + bh) * kHD + t];
    qn[t] = sqrtf(s);
  } else if (t < 96) {
    float s = 0.f;
    for (int c = 0; c < kNCH; ++c) s += ksqp[((size_t)c * 32 + bh) * kHD + (t - 48)];
    kinv[t - 48] = 1.f / fmaxf(sqrtf(s), 1e-12f);
  }
  __syncthreads();
  if (t < 48) {
    const float T = temp[hh];
    const float sqr = T / fmaxf(qn[t], 1e-12f);
    float m = -3.4e38f;
    for (int d = 0; d < kHD; ++d) {
      float v = S[t * kHD + d] * sqr * kinv[d];
      S[t * kHD + d] = v;
      m = fmaxf(m, v);
    }
    float sum = 0.f;
    for (int d = 0; d < kHD; ++d) {
      float e = expf(S[t * kHD + d] - m);
      S[t * kHD + d] = e;
      sum += e;
    }
    const float inv = 1.f / sum;
    float* A = attn + (size_t)bh * (kHD * kHD) + t * kHD;
    for (int d = 0; d < kHD; ++d) A[d] = S[t * kHD + d] * inv;
  }
}

// ---------------------------------------------------------------------------
// K4: M[b][o][j=hh*48+d] = sum_c w_out[o][hh*48+c] * attn[b,hh,c,d]  (bf16 out)
// ---------------------------------------------------------------------------
__global__ __launch_bounds__(256) void make_m(
    const float* __restrict__ wout, const float* __restrict__ attn, u16* __restrict__ M) {
  int g = blockIdx.x * 256 + threadIdx.x;
  if (g >= kB * kC * kC) return;
  int j = g % kC;
  int o = (g / kC) % kC;
  int b = g / (kC * kC);
  int hh = j / kHD, d = j % kHD;
  const float* A = attn + (size_t)(b * 4 + hh) * (kHD * kHD) + d;
  const float* wo = wout + (size_t)o * kC + hh * kHD;
  float s = 0.f;
#pragma unroll
  for (int c = 0; c < kHD; ++c) s += wo[c] * A[c * kHD];
  M[g] = f2bfu(s);
}

// ---------------------------------------------------------------------------
extern "C" void kernel_launch(void* const* d_in, const int* in_sizes, int n_in,
                              void* d_out, int out_size, void* d_ws, size_t ws_size,
                              hipStream_t stream) {
  const float* x    = (const float*)d_in[0];
  const float* wqkv = (const float*)d_in[1];
  const float* wdw  = (const float*)d_in[2];
  const float* temp = (const float*)d_in[3];
  const float* wout = (const float*)d_in[4];

  size_t off = 0;
  u16* qkv1 = (u16*)((char*)d_ws + off); off += (size_t)kB * kC3 * kHW * 2;  // 151 MB
  u16* qkv2 = (u16*)((char*)d_ws + off); off += (size_t)kB * kC3 * kHW * 2;  // 151 MB
  u16* xT   = (u16*)((char*)d_ws + off); off += (size_t)kB * kHW * kC * 2;   // 50 MB (xT, later vT)
  u16* Wq   = (u16*)((char*)d_ws + off); off += (size_t)kC3 * kC * 2;
  if (off > ws_size) return;  // insufficient workspace -> fail visibly
  u16* vT = xT;               // xT dead after K1

  // attention scratch aliases qkv1 (dead after K2)
  float* Spart = (float*)qkv1;                           // 64*32*2304*4 = 18.9 MB
  float* qsq   = Spart + (size_t)kNCH * 32 * kHD * kHD;
  float* ksq   = qsq + (size_t)kNCH * 32 * kHD;
  float* attn  = ksq + (size_t)kNCH * 32 * kHD;
  u16*   Mb    = (u16*)(attn + (size_t)32 * kHD * kHD);

  // P1/P2: weight cast + x transpose-cast
  cast_f32_bf16<<<dim3((kC3 * kC + 255) / 256), 256, 0, stream>>>(wqkv, Wq, kC3 * kC);
  transpose_cast_x<<<dim3(kHW / 64, kC / 64, kB), 256, 0, stream>>>(x, xT);
  // K1: qkv1 = Wq @ x (MFMA, bf16 out)
  gemm_mfma<true><<<dim3(kC3 / 64, kHW / 256, kB), 256, 0, stream>>>(
      Wq, 0L, xT, (long)kHW * kC, (void*)qkv1, (long)kC3 * kHW);
  // K2: depthwise 3x3
  dwconv3x3<<<dim3(kB * kC3 * kHW / 8 / 256), 256, 0, stream>>>(qkv1, wdw, qkv2);
  // K2b: vT = transpose(v)
  transpose_bf16<<<dim3(kHW / 64, kC / 64, kB), 256, 0, stream>>>(
      qkv2 + (size_t)2 * kC * kHW, (long)kC3 * kHW, vT, (long)kHW * kC);
  // K3: S partials + sumsq partials (MFMA)
  qk_mfma<<<dim3(kNCH, 32), 64, 0, stream>>>(qkv2, Spart, qsq, ksq);
  // K3b: reduce + normalize + softmax
  attn_softmax<<<dim3(32), 256, 0, stream>>>(Spart, qsq, ksq, temp, attn);
  // K4: M = w_out folded through attn (bf16)
  make_m<<<dim3((kB * kC * kC + 255) / 256), 256, 0, stream>>>(wout, attn, Mb);
  // K5: out = M @ v (MFMA, f32 out)
  gemm_mfma<false><<<dim3(kC / 64, kHW / 256, kB), 256, 0, stream>>>(
      Mb, (long)kC * kC, vT, (long)kHW * kC, d_out, (long)kC * kHW);
}